// Round 1
// baseline (317.870 us; speedup 1.0000x reference)
//
#include <hip/hip_runtime.h>
#include <hip/hip_bf16.h>

// Shapes: B=4, N=512, E=64; M = B*N = 2048; EN = E*E = 4096.
// out[b,i,j,o] = sum_{d1,d2} x[b,i,d1] * y[b,j,d2] * Wc[o, d1*64+d2] + bc[o]
// Factored:
//   U[(b,i)][o*64+d2] = sum_{d1} x[(b,i)][d1] * Wc[o, d1*64+d2]     (GEMM 2048x4096x64)
//   out[(b,i)][j][o]  = sum_{d2} Y_b[j][d2]   * U[(b,i)][o][d2] + bc[o]
// The second GEMM's [j][o] tile is exactly the contiguous output slice.

typedef __bf16 bf16x8 __attribute__((ext_vector_type(8)));
typedef unsigned short u16x8 __attribute__((ext_vector_type(8)));
typedef float f32x16 __attribute__((ext_vector_type(16)));

static __device__ inline unsigned short f2bf(float f) {
    unsigned int u = __float_as_uint(f);
    u = (u + 0x7FFFu + ((u >> 16) & 1u)) >> 16;   // RNE
    return (unsigned short)u;
}

static __device__ inline bf16x8 load_frag(const unsigned short* p) {
    u16x8 t = *(const u16x8*)p;     // 16B aligned by construction
    return __builtin_bit_cast(bf16x8, t);
}

// ---------------------------------------------------------------------------
// Kernel A: LayerNorm + gated projections. One wave per row (b,n).
// x[row][o] = h[o] * (dot(h, W1[o,:]) + b1[o]);  y likewise with W2/b2.
// ---------------------------------------------------------------------------
__global__ __launch_bounds__(256) void ln_gate_kernel(
    const float* __restrict__ emb, const float* __restrict__ g,
    const float* __restrict__ bln,
    const float* __restrict__ W1, const float* __restrict__ b1,
    const float* __restrict__ W2, const float* __restrict__ b2,
    unsigned short* __restrict__ xo, unsigned short* __restrict__ yo)
{
    __shared__ float hsh[4][64];
    const int wave = threadIdx.x >> 6;
    const int lane = threadIdx.x & 63;
    const int row  = blockIdx.x * 4 + wave;      // 0..2047

    float e = emb[row * 64 + lane];
    float s = e;
    #pragma unroll
    for (int m = 1; m < 64; m <<= 1) s += __shfl_xor(s, m);
    const float mu = s * (1.0f / 64.0f);
    const float d  = e - mu;
    float v = d * d;
    #pragma unroll
    for (int m = 1; m < 64; m <<= 1) v += __shfl_xor(v, m);
    const float rs = rsqrtf(v * (1.0f / 64.0f) + 1e-5f);
    const float h  = d * rs * g[lane] + bln[lane];

    hsh[wave][lane] = h;
    __syncthreads();

    const float4* hv  = (const float4*)hsh[wave];
    const float4* w1v = (const float4*)(W1 + lane * 64);   // lane = o
    const float4* w2v = (const float4*)(W2 + lane * 64);
    float d1 = 0.f, d2 = 0.f;
    #pragma unroll
    for (int k = 0; k < 16; k++) {
        float4 hh = hv[k];
        float4 a  = w1v[k];
        float4 c  = w2v[k];
        d1 += hh.x * a.x + hh.y * a.y + hh.z * a.z + hh.w * a.w;
        d2 += hh.x * c.x + hh.y * c.y + hh.z * c.z + hh.w * c.w;
    }
    xo[row * 64 + lane] = f2bf(h * (d1 + b1[lane]));
    yo[row * 64 + lane] = f2bf(h * (d2 + b2[lane]));
}

// ---------------------------------------------------------------------------
// Kernel P: rearrange Wc[o][d1*64+d2] (fp32) -> Wt[(o*64+d2)][d1] (bf16).
// One block per o; LDS transpose with +1 padding to kill bank conflicts.
// ---------------------------------------------------------------------------
__global__ __launch_bounds__(256) void wcprep_kernel(
    const float* __restrict__ Wc, unsigned short* __restrict__ wt)
{
    __shared__ float t[64][65];
    const int o = blockIdx.x;                    // 0..63
    const float* src = Wc + o * 4096;
    for (int w = threadIdx.x; w < 4096; w += 256)
        t[w >> 6][w & 63] = src[w];              // t[d1][d2]
    __syncthreads();
    unsigned short* dst = wt + o * 4096;         // dst[d2*64 + d1]
    for (int w = threadIdx.x; w < 4096; w += 256) {
        int d2 = w >> 6, d1 = w & 63;
        dst[w] = f2bf(t[d1][d2]);
    }
}

// ---------------------------------------------------------------------------
// Kernel B: U = X(2048x64) @ Wt^T(64x4096), bf16 MFMA, no LDS.
// Block = 4 waves covering 128x128; wave = 64x64 (2x2 tiles of 32x32, K=64).
// ---------------------------------------------------------------------------
__global__ __launch_bounds__(256) void ugemm_kernel(
    const unsigned short* __restrict__ x, const unsigned short* __restrict__ wt,
    unsigned short* __restrict__ u)
{
    const int wave = threadIdx.x >> 6;
    const int lane = threadIdx.x & 63;
    const int m0 = blockIdx.x * 128 + (wave >> 1) * 64;   // grid.x = 16
    const int n0 = blockIdx.y * 128 + (wave & 1) * 64;    // grid.y = 32
    const int lr = lane & 31, lh = lane >> 5;

    f32x16 acc[2][2] = {};
    #pragma unroll
    for (int ks = 0; ks < 4; ks++) {
        const int k = ks * 16 + lh * 8;
        bf16x8 a0 = load_frag(x  + (m0      + lr) * 64 + k);
        bf16x8 a1 = load_frag(x  + (m0 + 32 + lr) * 64 + k);
        bf16x8 b0 = load_frag(wt + (n0      + lr) * 64 + k);
        bf16x8 b1 = load_frag(wt + (n0 + 32 + lr) * 64 + k);
        acc[0][0] = __builtin_amdgcn_mfma_f32_32x32x16_bf16(a0, b0, acc[0][0], 0, 0, 0);
        acc[0][1] = __builtin_amdgcn_mfma_f32_32x32x16_bf16(a0, b1, acc[0][1], 0, 0, 0);
        acc[1][0] = __builtin_amdgcn_mfma_f32_32x32x16_bf16(a1, b0, acc[1][0], 0, 0, 0);
        acc[1][1] = __builtin_amdgcn_mfma_f32_32x32x16_bf16(a1, b1, acc[1][1], 0, 0, 0);
    }
    #pragma unroll
    for (int mi = 0; mi < 2; mi++)
        #pragma unroll
        for (int ni = 0; ni < 2; ni++)
            #pragma unroll
            for (int r = 0; r < 16; r++) {
                int row = m0 + mi * 32 + (r & 3) + 8 * (r >> 2) + 4 * lh;
                int col = n0 + ni * 32 + lr;
                u[row * 4096 + col] = f2bf(acc[mi][ni][r]);
            }
}

// ---------------------------------------------------------------------------
// Kernel C: out[(b,i)][j][o] = Y_b[j][d2] . U_{b,i}[o][d2] + bc[o].
// Block = 4 waves covering j-range 256 x o-range 64; wave = 64x64. No LDS.
// ---------------------------------------------------------------------------
__global__ __launch_bounds__(256) void out_kernel(
    const unsigned short* __restrict__ y, const unsigned short* __restrict__ u,
    const float* __restrict__ bc, float* __restrict__ out)
{
    const int wave = threadIdx.x >> 6;
    const int lane = threadIdx.x & 63;
    const int mp = blockIdx.y;                    // (b,i): 0..2047
    const int b  = mp >> 9;                       // N = 512
    const int j0 = blockIdx.x * 256 + wave * 64;  // grid.x = 2
    const int lr = lane & 31, lh = lane >> 5;

    const unsigned short* yb = y + b * (512 * 64);
    const unsigned short* ub = u + mp * 4096;

    f32x16 acc[2][2] = {};
    #pragma unroll
    for (int ks = 0; ks < 4; ks++) {
        const int k = ks * 16 + lh * 8;
        bf16x8 a0 = load_frag(yb + (j0      + lr) * 64 + k);
        bf16x8 a1 = load_frag(yb + (j0 + 32 + lr) * 64 + k);
        bf16x8 b0 = load_frag(ub + (lr)      * 64 + k);       // o in [0,32)
        bf16x8 b1 = load_frag(ub + (32 + lr) * 64 + k);       // o in [32,64)
        acc[0][0] = __builtin_amdgcn_mfma_f32_32x32x16_bf16(a0, b0, acc[0][0], 0, 0, 0);
        acc[0][1] = __builtin_amdgcn_mfma_f32_32x32x16_bf16(a0, b1, acc[0][1], 0, 0, 0);
        acc[1][0] = __builtin_amdgcn_mfma_f32_32x32x16_bf16(a1, b0, acc[1][0], 0, 0, 0);
        acc[1][1] = __builtin_amdgcn_mfma_f32_32x32x16_bf16(a1, b1, acc[1][1], 0, 0, 0);
    }

    const float bias0 = bc[lr];
    const float bias1 = bc[32 + lr];
    float* outp = out + (size_t)mp * 32768;       // out[b][i][j][o], j*64+o inside
    #pragma unroll
    for (int mi = 0; mi < 2; mi++)
        #pragma unroll
        for (int ni = 0; ni < 2; ni++) {
            const float bias = ni ? bias1 : bias0;
            const int col = ni * 32 + lr;
            #pragma unroll
            for (int r = 0; r < 16; r++) {
                int j = j0 + mi * 32 + (r & 3) + 8 * (r >> 2) + 4 * lh;
                outp[j * 64 + col] = acc[mi][ni][r] + bias;
            }
        }
}

// ---------------------------------------------------------------------------
extern "C" void kernel_launch(void* const* d_in, const int* in_sizes, int n_in,
                              void* d_out, int out_size, void* d_ws, size_t ws_size,
                              hipStream_t stream) {
    const float* emb  = (const float*)d_in[0];
    // d_in[1] = node_mask (unused by forward)
    const float* ln_g = (const float*)d_in[2];
    const float* ln_b = (const float*)d_in[3];
    const float* W1   = (const float*)d_in[4];
    const float* b1   = (const float*)d_in[5];
    const float* W2   = (const float*)d_in[6];
    const float* b2   = (const float*)d_in[7];
    const float* Wc   = (const float*)d_in[8];
    const float* bc   = (const float*)d_in[9];
    float* out = (float*)d_out;

    char* ws = (char*)d_ws;
    unsigned short* x_ws  = (unsigned short*)(ws);              // 2048*64*2  = 256 KB
    unsigned short* y_ws  = (unsigned short*)(ws + 262144);     // 256 KB
    unsigned short* wt_ws = (unsigned short*)(ws + 524288);     // 4096*64*2  = 512 KB
    unsigned short* u_ws  = (unsigned short*)(ws + 1048576);    // 2048*4096*2 = 16 MB

    hipLaunchKernelGGL(ln_gate_kernel, dim3(512), dim3(256), 0, stream,
                       emb, ln_g, ln_b, W1, b1, W2, b2, x_ws, y_ws);
    hipLaunchKernelGGL(wcprep_kernel, dim3(64), dim3(256), 0, stream, Wc, wt_ws);
    hipLaunchKernelGGL(ugemm_kernel, dim3(16, 32), dim3(256), 0, stream,
                       x_ws, wt_ws, u_ws);
    hipLaunchKernelGGL(out_kernel, dim3(2, 2048), dim3(256), 0, stream,
                       y_ws, u_ws, bc, out);
}

// Round 2
// 314.881 us; speedup vs baseline: 1.0095x; 1.0095x over previous
//
#include <hip/hip_runtime.h>
#include <hip/hip_bf16.h>

// Shapes: B=4, N=512, E=64; M = B*N = 2048; EN = E*E = 4096.
// out[b,i,j,o] = sum_{d1,d2} x[b,i,d1] * y[b,j,d2] * Wc[o, d1*64+d2] + bc[o]
// Factored:
//   U[(b,i)][o*64+d2] = sum_{d1} x[(b,i)][d1] * Wc[o, d1*64+d2]     (GEMM 2048x4096x64)
//   out[(b,i)][j][o]  = sum_{d2} Y_b[j][d2]   * U[(b,i)][o][d2] + bc[o]
// The second GEMM's [j][o] tile is exactly the contiguous output slice.

typedef __bf16 bf16x8 __attribute__((ext_vector_type(8)));
typedef unsigned short u16x8 __attribute__((ext_vector_type(8)));
typedef float f32x16 __attribute__((ext_vector_type(16)));

static __device__ inline unsigned short f2bf(float f) {
    unsigned int u = __float_as_uint(f);
    u = (u + 0x7FFFu + ((u >> 16) & 1u)) >> 16;   // RNE
    return (unsigned short)u;
}

static __device__ inline bf16x8 load_frag(const unsigned short* p) {
    u16x8 t = *(const u16x8*)p;     // 16B aligned by construction
    return __builtin_bit_cast(bf16x8, t);
}

// ---------------------------------------------------------------------------
// Kernel A: LayerNorm + gated projections. One wave per row (b,n).
// x[row][o] = h[o] * (dot(h, W1[o,:]) + b1[o]);  y likewise with W2/b2.
// ---------------------------------------------------------------------------
__global__ __launch_bounds__(256) void ln_gate_kernel(
    const float* __restrict__ emb, const float* __restrict__ g,
    const float* __restrict__ bln,
    const float* __restrict__ W1, const float* __restrict__ b1,
    const float* __restrict__ W2, const float* __restrict__ b2,
    unsigned short* __restrict__ xo, unsigned short* __restrict__ yo)
{
    __shared__ float hsh[4][64];
    const int wave = threadIdx.x >> 6;
    const int lane = threadIdx.x & 63;
    const int row  = blockIdx.x * 4 + wave;      // 0..2047

    float e = emb[row * 64 + lane];
    float s = e;
    #pragma unroll
    for (int m = 1; m < 64; m <<= 1) s += __shfl_xor(s, m);
    const float mu = s * (1.0f / 64.0f);
    const float d  = e - mu;
    float v = d * d;
    #pragma unroll
    for (int m = 1; m < 64; m <<= 1) v += __shfl_xor(v, m);
    const float rs = rsqrtf(v * (1.0f / 64.0f) + 1e-5f);
    const float h  = d * rs * g[lane] + bln[lane];

    hsh[wave][lane] = h;
    __syncthreads();

    const float4* hv  = (const float4*)hsh[wave];
    const float4* w1v = (const float4*)(W1 + lane * 64);   // lane = o
    const float4* w2v = (const float4*)(W2 + lane * 64);
    float d1 = 0.f, d2 = 0.f;
    #pragma unroll
    for (int k = 0; k < 16; k++) {
        float4 hh = hv[k];
        float4 a  = w1v[k];
        float4 c  = w2v[k];
        d1 += hh.x * a.x + hh.y * a.y + hh.z * a.z + hh.w * a.w;
        d2 += hh.x * c.x + hh.y * c.y + hh.z * c.z + hh.w * c.w;
    }
    xo[row * 64 + lane] = f2bf(h * (d1 + b1[lane]));
    yo[row * 64 + lane] = f2bf(h * (d2 + b2[lane]));
}

// ---------------------------------------------------------------------------
// Kernel P: rearrange Wc[o][d1*64+d2] (fp32) -> Wt[(o*64+d2)][d1] (bf16).
// One block per o; LDS transpose with +1 padding to kill bank conflicts.
// ---------------------------------------------------------------------------
__global__ __launch_bounds__(256) void wcprep_kernel(
    const float* __restrict__ Wc, unsigned short* __restrict__ wt)
{
    __shared__ float t[64][65];
    const int o = blockIdx.x;                    // 0..63
    const float* src = Wc + o * 4096;
    for (int w = threadIdx.x; w < 4096; w += 256)
        t[w >> 6][w & 63] = src[w];              // t[d1][d2]
    __syncthreads();
    unsigned short* dst = wt + o * 4096;         // dst[d2*64 + d1]
    for (int w = threadIdx.x; w < 4096; w += 256) {
        int d2 = w >> 6, d1 = w & 63;
        dst[w] = f2bf(t[d1][d2]);
    }
}

// ---------------------------------------------------------------------------
// Kernel B: U = X(2048x64) @ Wt^T(64x4096), bf16 MFMA, no LDS.
// Block = 4 waves covering 128x128; wave = 64x64 (2x2 tiles of 32x32, K=64).
// ---------------------------------------------------------------------------
__global__ __launch_bounds__(256) void ugemm_kernel(
    const unsigned short* __restrict__ x, const unsigned short* __restrict__ wt,
    unsigned short* __restrict__ u)
{
    const int wave = threadIdx.x >> 6;
    const int lane = threadIdx.x & 63;
    const int m0 = blockIdx.x * 128 + (wave >> 1) * 64;   // grid.x = 16
    const int n0 = blockIdx.y * 128 + (wave & 1) * 64;    // grid.y = 32
    const int lr = lane & 31, lh = lane >> 5;

    bf16x8 af[2][4], bf[2][4];
    #pragma unroll
    for (int ks = 0; ks < 4; ks++) {
        const int k = ks * 16 + lh * 8;
        af[0][ks] = load_frag(x  + (m0      + lr) * 64 + k);
        af[1][ks] = load_frag(x  + (m0 + 32 + lr) * 64 + k);
        bf[0][ks] = load_frag(wt + (n0      + lr) * 64 + k);
        bf[1][ks] = load_frag(wt + (n0 + 32 + lr) * 64 + k);
    }
    f32x16 acc[2][2] = {};
    #pragma unroll
    for (int ks = 0; ks < 4; ks++) {
        acc[0][0] = __builtin_amdgcn_mfma_f32_32x32x16_bf16(af[0][ks], bf[0][ks], acc[0][0], 0, 0, 0);
        acc[0][1] = __builtin_amdgcn_mfma_f32_32x32x16_bf16(af[0][ks], bf[1][ks], acc[0][1], 0, 0, 0);
        acc[1][0] = __builtin_amdgcn_mfma_f32_32x32x16_bf16(af[1][ks], bf[0][ks], acc[1][0], 0, 0, 0);
        acc[1][1] = __builtin_amdgcn_mfma_f32_32x32x16_bf16(af[1][ks], bf[1][ks], acc[1][1], 0, 0, 0);
    }
    #pragma unroll
    for (int mi = 0; mi < 2; mi++)
        #pragma unroll
        for (int ni = 0; ni < 2; ni++)
            #pragma unroll
            for (int r = 0; r < 16; r++) {
                int row = m0 + mi * 32 + (r & 3) + 8 * (r >> 2) + 4 * lh;
                int col = n0 + ni * 32 + lr;
                u[row * 4096 + col] = f2bf(acc[mi][ni][r]);
            }
}

// ---------------------------------------------------------------------------
// Kernel C: out[(b,i)][j][o] = Y_b[j][d2] . U_{b,i}[o][d2] + bc[o].
// grid (2048, 2): x = (b,i) so the 2 blocks sharing a U-tile differ by 2048
// in linear id (2048 % 8 == 0 -> same XCD -> L2 sharing of U).
// Output streamed with non-temporal stores (268 MB never re-read; keep it
// out of L2 so Y and U stay resident).
// ---------------------------------------------------------------------------
__global__ __launch_bounds__(256) void out_kernel(
    const unsigned short* __restrict__ y, const unsigned short* __restrict__ u,
    const float* __restrict__ bc, float* __restrict__ out)
{
    const int wave = threadIdx.x >> 6;
    const int lane = threadIdx.x & 63;
    const int mp = blockIdx.x;                    // (b,i): 0..2047
    const int b  = mp >> 9;                       // N = 512
    const int j0 = blockIdx.y * 256 + wave * 64;  // grid.y = 2
    const int lr = lane & 31, lh = lane >> 5;

    const unsigned short* yb = y + b * (512 * 64);
    const unsigned short* ub = u + mp * 4096;

    bf16x8 af[2][4], bf[2][4];
    #pragma unroll
    for (int ks = 0; ks < 4; ks++) {
        const int k = ks * 16 + lh * 8;
        af[0][ks] = load_frag(yb + (j0      + lr) * 64 + k);
        af[1][ks] = load_frag(yb + (j0 + 32 + lr) * 64 + k);
        bf[0][ks] = load_frag(ub + (lr)      * 64 + k);       // o in [0,32)
        bf[1][ks] = load_frag(ub + (32 + lr) * 64 + k);       // o in [32,64)
    }
    f32x16 acc[2][2] = {};
    #pragma unroll
    for (int ks = 0; ks < 4; ks++) {
        acc[0][0] = __builtin_amdgcn_mfma_f32_32x32x16_bf16(af[0][ks], bf[0][ks], acc[0][0], 0, 0, 0);
        acc[0][1] = __builtin_amdgcn_mfma_f32_32x32x16_bf16(af[0][ks], bf[1][ks], acc[0][1], 0, 0, 0);
        acc[1][0] = __builtin_amdgcn_mfma_f32_32x32x16_bf16(af[1][ks], bf[0][ks], acc[1][0], 0, 0, 0);
        acc[1][1] = __builtin_amdgcn_mfma_f32_32x32x16_bf16(af[1][ks], bf[1][ks], acc[1][1], 0, 0, 0);
    }

    const float bias0 = bc[lr];
    const float bias1 = bc[32 + lr];
    float* outp = out + (size_t)mp * 32768;       // out[b][i][j][o], j*64+o inside
    #pragma unroll
    for (int mi = 0; mi < 2; mi++)
        #pragma unroll
        for (int ni = 0; ni < 2; ni++) {
            const float bias = ni ? bias1 : bias0;
            const int col = ni * 32 + lr;
            #pragma unroll
            for (int r = 0; r < 16; r++) {
                int j = j0 + mi * 32 + (r & 3) + 8 * (r >> 2) + 4 * lh;
                __builtin_nontemporal_store(acc[mi][ni][r] + bias, &outp[j * 64 + col]);
            }
        }
}

// ---------------------------------------------------------------------------
extern "C" void kernel_launch(void* const* d_in, const int* in_sizes, int n_in,
                              void* d_out, int out_size, void* d_ws, size_t ws_size,
                              hipStream_t stream) {
    const float* emb  = (const float*)d_in[0];
    // d_in[1] = node_mask (unused by forward)
    const float* ln_g = (const float*)d_in[2];
    const float* ln_b = (const float*)d_in[3];
    const float* W1   = (const float*)d_in[4];
    const float* b1   = (const float*)d_in[5];
    const float* W2   = (const float*)d_in[6];
    const float* b2   = (const float*)d_in[7];
    const float* Wc   = (const float*)d_in[8];
    const float* bc   = (const float*)d_in[9];
    float* out = (float*)d_out;

    char* ws = (char*)d_ws;
    unsigned short* x_ws  = (unsigned short*)(ws);              // 2048*64*2  = 256 KB
    unsigned short* y_ws  = (unsigned short*)(ws + 262144);     // 256 KB
    unsigned short* wt_ws = (unsigned short*)(ws + 524288);     // 4096*64*2  = 512 KB
    unsigned short* u_ws  = (unsigned short*)(ws + 1048576);    // 2048*4096*2 = 16 MB

    hipLaunchKernelGGL(ln_gate_kernel, dim3(512), dim3(256), 0, stream,
                       emb, ln_g, ln_b, W1, b1, W2, b2, x_ws, y_ws);
    hipLaunchKernelGGL(wcprep_kernel, dim3(64), dim3(256), 0, stream, Wc, wt_ws);
    hipLaunchKernelGGL(ugemm_kernel, dim3(16, 32), dim3(256), 0, stream,
                       x_ws, wt_ws, u_ws);
    hipLaunchKernelGGL(out_kernel, dim3(2048, 2), dim3(256), 0, stream,
                       y_ws, u_ws, bc, out);
}